// Round 6
// baseline (384.622 us; speedup 1.0000x reference)
//
#include <hip/hip_runtime.h>
#include <cstdint>
#include <cstddef>

typedef int i32x4 __attribute__((ext_vector_type(4)));

static __device__ __forceinline__ int pack4(float4 v, float inv) {
  int a = __float2int_rn(v.x * inv) & 0xFF;
  int b = __float2int_rn(v.y * inv) & 0xFF;
  int c = __float2int_rn(v.z * inv) & 0xFF;
  int d = __float2int_rn(v.w * inv) & 0xFF;
  return a | (b << 8) | (c << 16) | (d << 24);
}

// ---------- prep fast path (K==4096): wave-per-row x quant + w pack ----------
__global__ __launch_bounds__(256) void prep_fast(
    const float* __restrict__ x, signed char* __restrict__ xq, float* __restrict__ xs,
    const int* __restrict__ w, signed char* __restrict__ wq,
    int xblocks) {
  const int t = threadIdx.x;
  if ((int)blockIdx.x < xblocks) {
    const int lane = t & 63;
    const int row  = ((int)blockIdx.x << 2) + (t >> 6);
    const float4* xr = (const float4*)(x + ((size_t)row << 12));
    float4 v[16];
#pragma unroll
    for (int i = 0; i < 16; ++i) v[i] = xr[(i << 6) + lane];
    float amax = 0.f;
#pragma unroll
    for (int i = 0; i < 16; ++i)
      amax = fmaxf(amax, fmaxf(fmaxf(fabsf(v[i].x), fabsf(v[i].y)),
                               fmaxf(fabsf(v[i].z), fabsf(v[i].w))));
#pragma unroll
    for (int off = 32; off > 0; off >>= 1)
      amax = fmaxf(amax, __shfl_xor(amax, off, 64));
    const float inv = (amax > 0.f) ? 127.f / amax : 0.f;
    if (lane == 0) xs[row] = amax / 127.f;
    int* o = (int*)(xq + ((size_t)row << 12));
#pragma unroll
    for (int i = 0; i < 16; ++i) o[(i << 6) + lane] = pack4(v[i], inv);
  } else {
    const size_t base = (((size_t)blockIdx.x - xblocks) << 10) + t;  // int4 units
    const int4* wp = (const int4*)w;
    int* op = (int*)wq;
#pragma unroll
    for (int i = 0; i < 4; ++i) {
      int4 vv = wp[base + (i << 8)];
      op[base + (i << 8)] = (vv.x & 0xFF) | ((vv.y & 0xFF) << 8) |
                            ((vv.z & 0xFF) << 16) | ((vv.w & 0xFF) << 24);
    }
  }
}

// ---------- prep general path (any K) ----------
__global__ __launch_bounds__(256) void prep_kernel(
    const float* __restrict__ x, signed char* __restrict__ xq, float* __restrict__ xs,
    const int* __restrict__ w, signed char* __restrict__ wq,
    int K, int xrows) {
  const int t = threadIdx.x;
  if ((int)blockIdx.x < xrows) {
    const int row = blockIdx.x;
    const float4* xr = (const float4*)(x + (size_t)row * K);
    const int n4 = K >> 2;
    __shared__ float wmax[4];
    float amax = 0.f;
    for (int i = t; i < n4; i += 256) {
      float4 v = xr[i];
      amax = fmaxf(amax, fmaxf(fmaxf(fabsf(v.x), fabsf(v.y)),
                               fmaxf(fabsf(v.z), fabsf(v.w))));
    }
#pragma unroll
    for (int off = 32; off > 0; off >>= 1)
      amax = fmaxf(amax, __shfl_xor(amax, off, 64));
    if ((t & 63) == 0) wmax[t >> 6] = amax;
    __syncthreads();
    amax = fmaxf(fmaxf(wmax[0], wmax[1]), fmaxf(wmax[2], wmax[3]));
    const float inv = (amax > 0.f) ? 127.f / amax : 0.f;
    if (t == 0) xs[row] = amax / 127.f;
    int* o = (int*)(xq + (size_t)row * K);
    for (int i = t; i < n4; i += 256) {
      float4 v = xr[i];
      o[i] = pack4(v, inv);
    }
  } else {
    const size_t g = (size_t)(blockIdx.x - xrows) * 256 + t;
    int4 v = ((const int4*)w)[g];
    ((int*)wq)[g] = (v.x & 0xFF) | ((v.y & 0xFF) << 8) |
                    ((v.z & 0xFF) << 16) | ((v.w & 0xFF) << 24);
  }
}

// ---------- async global->LDS, 16B per lane, wave-uniform LDS base ----------
static __device__ __forceinline__ void gld_lds16(const void* g, void* l) {
  __builtin_amdgcn_global_load_lds(
      (const __attribute__((address_space(1))) unsigned int*)g,
      (__attribute__((address_space(3))) unsigned int*)l,
      16, 0, 0);
}

// ---------- i8 NT GEMM, 256x256 tile, ONE-barrier/K-tile schedule ----------
// C[m][n] = xs[m]*ws[n] * sum_k Aq[m][k]*Bq[n][k]
// Evolves r5 (134.4us, MfmaUtil 44%, conflicts 0). Two changes, zero new regs:
//
// (1) ONE barrier per tile. r5's mid-tile barrier existed only because tile t
//     staged t+2 into the buffer being read. New staging: tile t stages ALL
//     FOUR groups of t+1 into buf[(t+1)&1], which is FULLY DEAD (its readers
//     completed before the previous end-of-tile barrier: every ds_read is
//     consumed by an MFMA issued before that barrier, so data is in regs).
//     No live region is ever written mid-tile -> mid barrier deleted. The
//     end-of-tile own-vmcnt(0)+barrier publishes t+1 AND (by the same
//     reads-consumed argument) licenses tile t+1 to stage into buf[t&1].
//     vmcnt(0) is cheap here, not a drain: the 8 loads issue at tile TOP,
//     ~4000cy before the wait (L3 service ~1200cy/CU); the "never vmcnt(0)
//     mid-loop" rule targets recently-issued loads. r5's vmcnt(4)/tail
//     special-case disappears.
// (2) A1 re-reads interleaved into MFMA0. MFMA half reordered i-outer
//     (blocks of 8: kh,nh,j inner -> dependent acc pairs 4 apart, same as
//     r5's spacing); after block i consumes af[i], re-read af[i] <- A1
//     (register WAR keeps program order; ds_read cannot complete before the
//     already-issued MFMAs read their operands). The 8 phase-B reads drain
//     under ~500cy of MFMA0 issue -> MFMA_HALF(1) starts stall-free.
//     This is r3's reuse idea WITHOUT r3's confounds (no sched_barrier(0)
//     pins, no blanket lgkmcnt drains).
// Frags (verified r1-r5): A/B lane=row(lane&15), k-chunk (lane>>4)*16B;
// C/D col=lane&15, row=(lane>>4)*4+reg. 16-row column reads = max
// conflict-free height at 128B row stride (r4 lesson); chunk^(row&7)
// swizzle -> 2 lanes/16B slot = free (measured 0). int32 dot exact.
__global__ __launch_bounds__(512, 2) void gemm_i8_1b(
    const signed char* __restrict__ A,   // [M,K] i8
    const signed char* __restrict__ B,   // [N,K] i8
    const float* __restrict__ xs,        // [M] row scales
    const float* __restrict__ ws,        // [N] col scales
    float* __restrict__ C,               // [M,N] fp32
    int M, int N, int K) {
  __shared__ __align__(16) signed char lds[131072];

  const int tid  = threadIdx.x;
  const int lane = tid & 63;
  const int wave = tid >> 6;
  const int wm   = wave >> 2;          // 0..1
  const int wn   = wave & 3;           // 0..3
  const int q    = lane >> 4;          // 0..3 (16B k-chunk)
  const int r16  = lane & 15;
  const int e    = lane & 7;

  // bijective XCD swizzle (nwg = 512 = 8*64 exact; guarded)
  const unsigned nwg = gridDim.x * gridDim.y;
  unsigned id = blockIdx.y * gridDim.x + blockIdx.x;
  if ((nwg & 7u) == 0u) id = (id & 7u) * (nwg >> 3) + (id >> 3);
  const int m0 = (int)(id / gridDim.x) << 8;
  const int n0 = (int)(id % gridDim.x) << 8;

  const int NT = K >> 7;               // K-tiles of 128

  // staging: thread -> row tid>>3 (of 64), chunk tid&7, global pre-swizzled
  const int srow   = tid >> 3;
  const int schunk = ((tid & 7) ^ (srow & 7)) << 4;
  const signed char* sA = A + (size_t)(m0 + srow) * K + schunk;
  const signed char* sB = B + (size_t)(n0 + srow) * K + schunk;
  signed char* lW = lds + wave * 1024;  // wave-uniform LDS base

  // reader offsets: A row = mt*32 + wm*16 + r16 ; B row = nh*128+wn*32+j*16+r16
  const int aro = ((wm << 4) + r16) << 7;
  const int bro = r16 << 7;
  const int cs  = (q ^ e) << 4;        // swizzled chunk, kh0 (kh1 = ^64)

  i32x4 acc[8][4];
#pragma unroll
  for (int i = 0; i < 8; ++i)
#pragma unroll
    for (int j = 0; j < 4; ++j) acc[i][j] = (i32x4){0, 0, 0, 0};
  i32x4 af[4][2], bf[2][2][2];

// stage group g of tile Tv: g 0=A-half0 1=B-half0 2=A-half1 3=B-half1
#define STAGE(Tv, Gv)                                                        \
  do {                                                                       \
    const int t_ = (Tv);                                                     \
    if (t_ < NT) {                                                           \
      const int mat_ = (Gv) & 1, half_ = (Gv) >> 1;                          \
      signed char* l_ = lW + ((t_ & 1) << 15) + (mat_ << 16) + (half_ << 14);\
      const signed char* g_ = (mat_ ? sB : sA) +                             \
                              (size_t)(half_ << 7) * K + ((size_t)t_ << 7);  \
      gld_lds16(g_, l_);                                                     \
      gld_lds16(g_ + (size_t)64 * K, l_ + 8192);                             \
    }                                                                        \
  } while (0)

#define READ_A(MH)                                                           \
  _Pragma("unroll") for (int i_ = 0; i_ < 4; ++i_)                           \
    _Pragma("unroll") for (int kh_ = 0; kh_ < 2; ++kh_)                      \
      af[i_][kh_] = *(const i32x4*)(pA + ((((MH) << 2) + i_) << 12) + aro +  \
                                    (cs ^ (kh_ << 6)));

// re-read ONE A1 frag pair into af[IV] (after MFMA block IV consumed it)
#define RDA1(IV)                                                             \
  _Pragma("unroll") for (int kh_ = 0; kh_ < 2; ++kh_)                        \
    af[IV][kh_] = *(const i32x4*)(pA + ((4 + (IV)) << 12) + aro +            \
                                  (cs ^ (kh_ << 6)));

#define READ_B                                                               \
  _Pragma("unroll") for (int nh_ = 0; nh_ < 2; ++nh_)                        \
    _Pragma("unroll") for (int j_ = 0; j_ < 2; ++j_)                         \
      _Pragma("unroll") for (int kh_ = 0; kh_ < 2; ++kh_)                    \
        bf[nh_][j_][kh_] = *(const i32x4*)(pB + (nh_ << 14) + (wn << 12) +   \
                                           (j_ << 11) + bro + (cs ^ (kh_ << 6)));

// 8 MFMAs: output row block (MH*4+IV), all 4 col tiles, both k-halves.
// kh outer -> dependent acc pairs are 4 issues apart (r5-verified spacing).
#define MFMA_I(MH, IV)                                                       \
  _Pragma("unroll") for (int kh_ = 0; kh_ < 2; ++kh_)                        \
    _Pragma("unroll") for (int nh_ = 0; nh_ < 2; ++nh_)                      \
      _Pragma("unroll") for (int j_ = 0; j_ < 2; ++j_)                       \
        acc[((MH) << 2) + (IV)][(nh_ << 1) + j_] =                           \
            __builtin_amdgcn_mfma_i32_16x16x64_i8(                           \
                af[IV][kh_], bf[nh_][j_][kh_],                               \
                acc[((MH) << 2) + (IV)][(nh_ << 1) + j_], 0, 0, 0);

  // prologue: stage tile0 only; full drain once (cold)
  STAGE(0, 0); STAGE(0, 1); STAGE(0, 2); STAGE(0, 3);
  asm volatile("s_waitcnt vmcnt(0)" ::: "memory");
  __builtin_amdgcn_s_barrier();

  for (int t = 0; t < NT; ++t) {
    const signed char* pA = lds + ((t & 1) << 15);
    const signed char* pB = lds + 65536 + ((t & 1) << 15);
    // stage ALL of tile t+1 at tile top (dead buffer; ~full-tile lead)
    STAGE(t + 1, 0); STAGE(t + 1, 1); STAGE(t + 1, 2); STAGE(t + 1, 3);
    READ_A(0);
    READ_B;
    __builtin_amdgcn_s_setprio(1);
    MFMA_I(0, 0); RDA1(0);      // re-read af[0] <- A1 under MFMA issue
    MFMA_I(0, 1); RDA1(1);
    MFMA_I(0, 2); RDA1(2);
    MFMA_I(0, 3); RDA1(3);
    MFMA_I(1, 0);
    MFMA_I(1, 1);
    MFMA_I(1, 2);
    MFMA_I(1, 3);
    __builtin_amdgcn_s_setprio(0);
    // own stage loads done (issued ~4000cy ago) -> publish tile t+1.
    // Barrier also certifies all waves consumed buf[t&1] (every ds_read was
    // consumed by an MFMA issued above) -> next tile may stage into it.
    asm volatile("s_waitcnt vmcnt(0)" ::: "memory");
    __builtin_amdgcn_s_barrier();
  }
#undef MFMA_I
#undef READ_B
#undef RDA1
#undef READ_A
#undef STAGE

  // epilogue: C/D col=lane&15, row=(lane>>4)*4+reg; out = acc*xs[row]*ws[col]
#pragma unroll
  for (int mt = 0; mt < 8; ++mt) {
    const int row0 = m0 + (mt << 5) + (wm << 4) + (q << 2);
    float xv[4];
#pragma unroll
    for (int r = 0; r < 4; ++r) xv[r] = xs[row0 + r];
#pragma unroll
    for (int nt = 0; nt < 4; ++nt) {
      const int col = n0 + ((nt >> 1) << 7) + (wn << 5) + ((nt & 1) << 4) + r16;
      const float s = ws[col];
      float* Cp = C + (size_t)row0 * N + col;
#pragma unroll
      for (int r = 0; r < 4; ++r)
        Cp[(size_t)r * N] = (float)acc[mt][nt][r] * xv[r] * s;
    }
  }
}

// ---------- fallback (odd shapes) ----------
__global__ void naive_kernel(const float* __restrict__ x, const int* __restrict__ w,
                             const float* __restrict__ sc, float* __restrict__ out,
                             int M, int N, int K) {
  int idx = blockIdx.x * 256 + threadIdx.x;
  if (idx >= M * N) return;
  int m = idx / N, n = idx % N;
  const float* xr = x + (size_t)m * K;
  const int*   wr = w + (size_t)n * K;
  float acc = 0.f;
  for (int k = 0; k < K; ++k) acc += xr[k] * (float)wr[k];
  out[idx] = acc * sc[n];
}

extern "C" void kernel_launch(void* const* d_in, const int* in_sizes, int n_in,
                              void* d_out, int out_size, void* d_ws, size_t ws_size,
                              hipStream_t stream) {
  const float* x  = (const float*)d_in[0];
  const int*   w  = (const int*)d_in[1];
  const float* sc = (const float*)d_in[2];
  float* out = (float*)d_out;

  const int N = in_sizes[2];          // D_OUT
  const int K = in_sizes[1] / N;      // D_IN
  const int M = in_sizes[0] / K;      // B*S

  const size_t need = (size_t)M * K + (size_t)N * K + (size_t)M * 4 + 16;
  if (ws_size < need || (M & 255) || (N & 255) || (K & 127) || K < 256 ||
      (((size_t)N * K) % 1024)) {
    int total = M * N;
    naive_kernel<<<(total + 255) / 256, 256, 0, stream>>>(x, w, sc, out, M, N, K);
    return;
  }

  signed char* xq = (signed char*)d_ws;
  signed char* wq = xq + (size_t)M * K;
  float*       xsc = (float*)(wq + (size_t)N * K);

  if (K == 4096 && (M & 3) == 0 && (((size_t)N * K) % 4096) == 0) {
    const int xblocks = M >> 2;                         // one wave per row
    const int wblocks = (int)(((size_t)N * K) >> 12);   // 4 int4 per thread
    prep_fast<<<xblocks + wblocks, 256, 0, stream>>>(x, xq, xsc, w, wq, xblocks);
  } else {
    const int wblocks = (int)(((size_t)N * K) / 1024);
    prep_kernel<<<M + wblocks, 256, 0, stream>>>(x, xq, xsc, w, wq, K, M);
  }

  dim3 grid(N >> 8, M >> 8);
  gemm_i8_1b<<<grid, 512, 0, stream>>>(xq, wq, xsc, sc, out, M, N, K);
}

// Round 7
// 384.269 us; speedup vs baseline: 1.0009x; 1.0009x over previous
//
#include <hip/hip_runtime.h>
#include <cstdint>
#include <cstddef>

typedef int i32x4 __attribute__((ext_vector_type(4)));

static __device__ __forceinline__ int pack4(float4 v, float inv) {
  int a = __float2int_rn(v.x * inv) & 0xFF;
  int b = __float2int_rn(v.y * inv) & 0xFF;
  int c = __float2int_rn(v.z * inv) & 0xFF;
  int d = __float2int_rn(v.w * inv) & 0xFF;
  return a | (b << 8) | (c << 16) | (d << 24);
}

// ---------- prep fast path (K==4096): wave-per-row x quant + w pack ----------
__global__ __launch_bounds__(256) void prep_fast(
    const float* __restrict__ x, signed char* __restrict__ xq, float* __restrict__ xs,
    const int* __restrict__ w, signed char* __restrict__ wq,
    int xblocks) {
  const int t = threadIdx.x;
  if ((int)blockIdx.x < xblocks) {
    const int lane = t & 63;
    const int row  = ((int)blockIdx.x << 2) + (t >> 6);
    const float4* xr = (const float4*)(x + ((size_t)row << 12));
    float4 v[16];
#pragma unroll
    for (int i = 0; i < 16; ++i) v[i] = xr[(i << 6) + lane];
    float amax = 0.f;
#pragma unroll
    for (int i = 0; i < 16; ++i)
      amax = fmaxf(amax, fmaxf(fmaxf(fabsf(v[i].x), fabsf(v[i].y)),
                               fmaxf(fabsf(v[i].z), fabsf(v[i].w))));
#pragma unroll
    for (int off = 32; off > 0; off >>= 1)
      amax = fmaxf(amax, __shfl_xor(amax, off, 64));
    const float inv = (amax > 0.f) ? 127.f / amax : 0.f;
    if (lane == 0) xs[row] = amax / 127.f;
    int* o = (int*)(xq + ((size_t)row << 12));
#pragma unroll
    for (int i = 0; i < 16; ++i) o[(i << 6) + lane] = pack4(v[i], inv);
  } else {
    const size_t base = (((size_t)blockIdx.x - xblocks) << 10) + t;  // int4 units
    const int4* wp = (const int4*)w;
    int* op = (int*)wq;
#pragma unroll
    for (int i = 0; i < 4; ++i) {
      int4 vv = wp[base + (i << 8)];
      op[base + (i << 8)] = (vv.x & 0xFF) | ((vv.y & 0xFF) << 8) |
                            ((vv.z & 0xFF) << 16) | ((vv.w & 0xFF) << 24);
    }
  }
}

// ---------- prep general path (any K) ----------
__global__ __launch_bounds__(256) void prep_kernel(
    const float* __restrict__ x, signed char* __restrict__ xq, float* __restrict__ xs,
    const int* __restrict__ w, signed char* __restrict__ wq,
    int K, int xrows) {
  const int t = threadIdx.x;
  if ((int)blockIdx.x < xrows) {
    const int row = blockIdx.x;
    const float4* xr = (const float4*)(x + (size_t)row * K);
    const int n4 = K >> 2;
    __shared__ float wmax[4];
    float amax = 0.f;
    for (int i = t; i < n4; i += 256) {
      float4 v = xr[i];
      amax = fmaxf(amax, fmaxf(fmaxf(fabsf(v.x), fabsf(v.y)),
                               fmaxf(fabsf(v.z), fabsf(v.w))));
    }
#pragma unroll
    for (int off = 32; off > 0; off >>= 1)
      amax = fmaxf(amax, __shfl_xor(amax, off, 64));
    if ((t & 63) == 0) wmax[t >> 6] = amax;
    __syncthreads();
    amax = fmaxf(fmaxf(wmax[0], wmax[1]), fmaxf(wmax[2], wmax[3]));
    const float inv = (amax > 0.f) ? 127.f / amax : 0.f;
    if (t == 0) xs[row] = amax / 127.f;
    int* o = (int*)(xq + (size_t)row * K);
    for (int i = t; i < n4; i += 256) {
      float4 v = xr[i];
      o[i] = pack4(v, inv);
    }
  } else {
    const size_t g = (size_t)(blockIdx.x - xrows) * 256 + t;
    int4 v = ((const int4*)w)[g];
    ((int*)wq)[g] = (v.x & 0xFF) | ((v.y & 0xFF) << 8) |
                    ((v.z & 0xFF) << 16) | ((v.w & 0xFF) << 24);
  }
}

// ---------- async global->LDS, 16B per lane, wave-uniform LDS base ----------
static __device__ __forceinline__ void gld_lds16(const void* g, void* l) {
  __builtin_amdgcn_global_load_lds(
      (const __attribute__((address_space(1))) unsigned int*)g,
      (__attribute__((address_space(3))) unsigned int*)l,
      16, 0, 0);
}

// ---------- i8 NT GEMM, 256x256 tile, r5 skeleton + RDA1-under-MFMA0 ----------
// C[m][n] = xs[m]*ws[n] * sum_k Aq[m][k]*Bq[n][k]
// Base = r5's VERIFIED schedule (134.4us, MfmaUtil 44%, conflicts 0): split
// staging {t+1.A1B1 pre-bar, t+2.A0B0 post-bar}, counted vmcnt(4), mid+end
// barriers. r6 isolated nothing (deleted mid barrier AND counted vmcnt AND
// burst-staged: net regression) -> reverted.
// ONE change vs r5: the 8 A1 frag re-reads issue interleaved under the MFMA0
// cluster (r6's RDA1, never tested alone). Register WAR: af[i] re-loads
// AFTER the MFMAs consuming it are issued; in-order lgkm makes MFMA_I(1,*)
// wait correctly. A1 region of buf[t&1] is live-published and nothing writes
// it during tile t (t+1 stages -> other buffer; t+2 stages -> A0/B0 only).
// Phase B then has ZERO LDS waits: STAGE + 32 MFMA back-to-back, removing
// r5's ~300cy post-barrier read stall.
// Barrier roles (unchanged from r5): mid barrier certifies every wave's
// phase-A reads (A0+B0 regions) completed -- a wave reaches it only after
// issuing all of MFMA0, whose operands require those ds_reads complete ->
// STAGE(t+2,A0B0) overwrite is safe. End barrier: own-vmcnt + barrier
// publishes tile t+1. vmcnt ledger: end-of-t outstanding = [t+1.A0B0]
// [t+1.A1B1][t+2.A0B0] = 12 -> vmcnt(4) retires the 8 oldest = ALL of tile
// t+1, 4 stay in flight. Tail t>=NT-2: t+2 guarded out -> vmcnt(0).
// Frags (verified r1-r6): A/B lane=row(lane&15), k-chunk (lane>>4)*16B;
// C/D col=lane&15, row=(lane>>4)*4+reg. 16-row column reads = max
// conflict-free height at 128B row stride (r4 lesson); chunk^(row&7)
// swizzle -> 2 lanes/16B slot = free (measured 0). int32 dot exact.
__global__ __launch_bounds__(512, 2) void gemm_i8_ds2(
    const signed char* __restrict__ A,   // [M,K] i8
    const signed char* __restrict__ B,   // [N,K] i8
    const float* __restrict__ xs,        // [M] row scales
    const float* __restrict__ ws,        // [N] col scales
    float* __restrict__ C,               // [M,N] fp32
    int M, int N, int K) {
  __shared__ __align__(16) signed char lds[131072];

  const int tid  = threadIdx.x;
  const int lane = tid & 63;
  const int wave = tid >> 6;
  const int wm   = wave >> 2;          // 0..1
  const int wn   = wave & 3;           // 0..3
  const int q    = lane >> 4;          // 0..3 (16B k-chunk)
  const int r16  = lane & 15;
  const int e    = lane & 7;

  // bijective XCD swizzle (nwg = 512 = 8*64 exact; guarded)
  const unsigned nwg = gridDim.x * gridDim.y;
  unsigned id = blockIdx.y * gridDim.x + blockIdx.x;
  if ((nwg & 7u) == 0u) id = (id & 7u) * (nwg >> 3) + (id >> 3);
  const int m0 = (int)(id / gridDim.x) << 8;
  const int n0 = (int)(id % gridDim.x) << 8;

  const int NT = K >> 7;               // K-tiles of 128

  // staging: thread -> row tid>>3 (of 64), chunk tid&7, global pre-swizzled
  const int srow   = tid >> 3;
  const int schunk = ((tid & 7) ^ (srow & 7)) << 4;
  const signed char* sA = A + (size_t)(m0 + srow) * K + schunk;
  const signed char* sB = B + (size_t)(n0 + srow) * K + schunk;
  signed char* lW = lds + wave * 1024;  // wave-uniform LDS base

  // reader offsets: A row = mt*32 + wm*16 + r16 ; B row = nh*128+wn*32+j*16+r16
  const int aro = ((wm << 4) + r16) << 7;
  const int bro = r16 << 7;
  const int cs  = (q ^ e) << 4;        // swizzled chunk, kh0 (kh1 = ^64)

  i32x4 acc[8][4];
#pragma unroll
  for (int i = 0; i < 8; ++i)
#pragma unroll
    for (int j = 0; j < 4; ++j) acc[i][j] = (i32x4){0, 0, 0, 0};
  i32x4 af[4][2], bf[2][2][2];

// stage group g of tile Tv: g 0=A-half0 1=B-half0 2=A-half1 3=B-half1
#define STAGE(Tv, Gv)                                                        \
  do {                                                                       \
    const int t_ = (Tv);                                                     \
    if (t_ < NT) {                                                           \
      const int mat_ = (Gv) & 1, half_ = (Gv) >> 1;                          \
      signed char* l_ = lW + ((t_ & 1) << 15) + (mat_ << 16) + (half_ << 14);\
      const signed char* g_ = (mat_ ? sB : sA) +                             \
                              (size_t)(half_ << 7) * K + ((size_t)t_ << 7);  \
      gld_lds16(g_, l_);                                                     \
      gld_lds16(g_ + (size_t)64 * K, l_ + 8192);                             \
    }                                                                        \
  } while (0)

#define READ_A(MH)                                                           \
  _Pragma("unroll") for (int i_ = 0; i_ < 4; ++i_)                           \
    _Pragma("unroll") for (int kh_ = 0; kh_ < 2; ++kh_)                      \
      af[i_][kh_] = *(const i32x4*)(pA + ((((MH) << 2) + i_) << 12) + aro +  \
                                    (cs ^ (kh_ << 6)));

// re-read ONE A1 frag pair into af[IV] (after MFMA block IV consumed it)
#define RDA1(IV)                                                             \
  _Pragma("unroll") for (int kh_ = 0; kh_ < 2; ++kh_)                        \
    af[IV][kh_] = *(const i32x4*)(pA + ((4 + (IV)) << 12) + aro +            \
                                  (cs ^ (kh_ << 6)));

#define READ_B                                                               \
  _Pragma("unroll") for (int nh_ = 0; nh_ < 2; ++nh_)                        \
    _Pragma("unroll") for (int j_ = 0; j_ < 2; ++j_)                         \
      _Pragma("unroll") for (int kh_ = 0; kh_ < 2; ++kh_)                    \
        bf[nh_][j_][kh_] = *(const i32x4*)(pB + (nh_ << 14) + (wn << 12) +   \
                                           (j_ << 11) + bro + (cs ^ (kh_ << 6)));

// 8 MFMAs: output row block (MH*4+IV), all 4 col tiles, both k-halves.
// kh outer -> dependent acc pairs 4 issues apart (r5/r6-verified spacing).
#define MFMA_I(MH, IV)                                                       \
  _Pragma("unroll") for (int kh_ = 0; kh_ < 2; ++kh_)                        \
    _Pragma("unroll") for (int nh_ = 0; nh_ < 2; ++nh_)                      \
      _Pragma("unroll") for (int j_ = 0; j_ < 2; ++j_)                       \
        acc[((MH) << 2) + (IV)][(nh_ << 1) + j_] =                           \
            __builtin_amdgcn_mfma_i32_16x16x64_i8(                           \
                af[IV][kh_], bf[nh_][j_][kh_],                               \
                acc[((MH) << 2) + (IV)][(nh_ << 1) + j_], 0, 0, 0);

  // prologue: tile0 all + tile1 {A0,B0}; vmcnt(4) retires the 8 tile0 loads
  STAGE(0, 0); STAGE(0, 1); STAGE(0, 2); STAGE(0, 3);
  STAGE(1, 0); STAGE(1, 1);
  asm volatile("s_waitcnt vmcnt(4)" ::: "memory");
  __builtin_amdgcn_s_barrier();

  for (int t = 0; t < NT; ++t) {
    const signed char* pA = lds + ((t & 1) << 15);
    const signed char* pB = lds + 65536 + ((t & 1) << 15);
    // ---- phase A: mh0 reads + MFMA0, with A1 re-reads drained under MFMA0
    READ_A(0);
    READ_B;
    STAGE(t + 1, 2); STAGE(t + 1, 3);          // t+1.A1, t+1.B1 (dead buffer)
    __builtin_amdgcn_s_setprio(1);
    MFMA_I(0, 0); RDA1(0);
    MFMA_I(0, 1); RDA1(1);
    MFMA_I(0, 2); RDA1(2);
    MFMA_I(0, 3); RDA1(3);
    __builtin_amdgcn_s_setprio(0);
    __builtin_amdgcn_s_barrier();              // all waves' phase-A reads consumed
    // ---- phase B: pure STAGE + MFMA (A1 already in regs)
    STAGE(t + 2, 0); STAGE(t + 2, 1);          // overwrite buf[t&1].A0/B0: safe
    __builtin_amdgcn_s_setprio(1);
    MFMA_I(1, 0);
    MFMA_I(1, 1);
    MFMA_I(1, 2);
    MFMA_I(1, 3);
    __builtin_amdgcn_s_setprio(0);
    if (t < NT - 2) asm volatile("s_waitcnt vmcnt(4)" ::: "memory");
    else            asm volatile("s_waitcnt vmcnt(0)" ::: "memory");
    __builtin_amdgcn_s_barrier();              // publish tile t+1
  }
#undef MFMA_I
#undef READ_B
#undef RDA1
#undef READ_A
#undef STAGE

  // epilogue: C/D col=lane&15, row=(lane>>4)*4+reg; out = acc*xs[row]*ws[col]
#pragma unroll
  for (int mt = 0; mt < 8; ++mt) {
    const int row0 = m0 + (mt << 5) + (wm << 4) + (q << 2);
    float xv[4];
#pragma unroll
    for (int r = 0; r < 4; ++r) xv[r] = xs[row0 + r];
#pragma unroll
    for (int nt = 0; nt < 4; ++nt) {
      const int col = n0 + ((nt >> 1) << 7) + (wn << 5) + ((nt & 1) << 4) + r16;
      const float s = ws[col];
      float* Cp = C + (size_t)row0 * N + col;
#pragma unroll
      for (int r = 0; r < 4; ++r)
        Cp[(size_t)r * N] = (float)acc[mt][nt][r] * xv[r] * s;
    }
  }
}

// ---------- fallback (odd shapes) ----------
__global__ void naive_kernel(const float* __restrict__ x, const int* __restrict__ w,
                             const float* __restrict__ sc, float* __restrict__ out,
                             int M, int N, int K) {
  int idx = blockIdx.x * 256 + threadIdx.x;
  if (idx >= M * N) return;
  int m = idx / N, n = idx % N;
  const float* xr = x + (size_t)m * K;
  const int*   wr = w + (size_t)n * K;
  float acc = 0.f;
  for (int k = 0; k < K; ++k) acc += xr[k] * (float)wr[k];
  out[idx] = acc * sc[n];
}

extern "C" void kernel_launch(void* const* d_in, const int* in_sizes, int n_in,
                              void* d_out, int out_size, void* d_ws, size_t ws_size,
                              hipStream_t stream) {
  const float* x  = (const float*)d_in[0];
  const int*   w  = (const int*)d_in[1];
  const float* sc = (const float*)d_in[2];
  float* out = (float*)d_out;

  const int N = in_sizes[2];          // D_OUT
  const int K = in_sizes[1] / N;      // D_IN
  const int M = in_sizes[0] / K;      // B*S

  const size_t need = (size_t)M * K + (size_t)N * K + (size_t)M * 4 + 16;
  if (ws_size < need || (M & 255) || (N & 255) || (K & 127) || K < 256 ||
      (((size_t)N * K) % 1024)) {
    int total = M * N;
    naive_kernel<<<(total + 255) / 256, 256, 0, stream>>>(x, w, sc, out, M, N, K);
    return;
  }

  signed char* xq = (signed char*)d_ws;
  signed char* wq = xq + (size_t)M * K;
  float*       xsc = (float*)(wq + (size_t)N * K);

  if (K == 4096 && (M & 3) == 0 && (((size_t)N * K) % 4096) == 0) {
    const int xblocks = M >> 2;                         // one wave per row
    const int wblocks = (int)(((size_t)N * K) >> 12);   // 4 int4 per thread
    prep_fast<<<xblocks + wblocks, 256, 0, stream>>>(x, xq, xsc, w, wq, xblocks);
  } else {
    const int wblocks = (int)(((size_t)N * K) / 1024);
    prep_kernel<<<M + wblocks, 256, 0, stream>>>(x, xq, xsc, w, wq, K, M);
  }

  dim3 grid(N >> 8, M >> 8);
  gemm_i8_ds2<<<grid, 512, 0, stream>>>(xq, wq, xsc, sc, out, M, N, K);
}